// Round 21
// baseline (1240.417 us; speedup 1.0000x reference)
//
#include <hip/hip_runtime.h>
#include <stdint.h>

// ---- Problem constants -------------------------------------------------
#define DIM   1536
#define NQ    6272      // 8 * 28 * 28 queries
#define NQP   6400      // padded to 50 * 128
#define NB    50000     // bank rows
#define NBP2  50176     // padded to 196 * 256
#define MT3   50
#define NT3   196
#define GRID3 (MT3 * NT3)   // 9800
#define NPIX  (8 * 224 * 224)

typedef float f32x4 __attribute__((ext_vector_type(4)));
typedef int   i32x4 __attribute__((ext_vector_type(4)));
typedef __attribute__((address_space(3))) signed char lds_i8;

__device__ inline void gll16(const signed char* g, signed char* l) {
  __builtin_amdgcn_global_load_lds(
      (const __attribute__((address_space(1))) uint32_t*)g,
      (__attribute__((address_space(3))) uint32_t*)l, 16, 0, 0);
}

// ---- init: minbits = +inf, image scores = 0 ---------------------------
__global__ void init_kernel(uint32_t* __restrict__ minbits, float* __restrict__ out_scores) {
  int i = blockIdx.x * 256 + threadIdx.x;
  if (i < NQP) minbits[i] = 0x7F800000u;   // +inf
  if (i < 8)   out_scores[i] = 0.0f;
}

// ---- fp32 -> int8 row quantization + fp32 row norms + scales ----------
__global__ void quant_rows(const float* __restrict__ src, signed char* __restrict__ dst,
                           float* __restrict__ norms, float* __restrict__ scales,
                           int nsrc, int ndst) {
  int row  = blockIdx.x * 4 + (threadIdx.x >> 6);
  int lane = threadIdx.x & 63;
  if (row >= ndst) return;
  uint32_t* drow = (uint32_t*)(dst + (size_t)row * DIM);
  if (row < nsrc) {
    const float4* s = (const float4*)(src + (size_t)row * DIM);
    float4 v[6]; float ns = 0.f, mx = 0.f;
#pragma unroll
    for (int i = 0; i < 6; ++i) {
      v[i] = s[lane + 64 * i];
      ns += v[i].x * v[i].x + v[i].y * v[i].y + v[i].z * v[i].z + v[i].w * v[i].w;
      mx = fmaxf(mx, fmaxf(fmaxf(fabsf(v[i].x), fabsf(v[i].y)),
                           fmaxf(fabsf(v[i].z), fabsf(v[i].w))));
    }
#pragma unroll
    for (int off = 32; off >= 1; off >>= 1) {
      ns += __shfl_xor(ns, off);
      mx = fmaxf(mx, __shfl_xor(mx, off));
    }
    float inv = (mx > 0.f) ? 127.0f / mx : 0.f;
#pragma unroll
    for (int i = 0; i < 6; ++i) {
      int a = max(-127, min(127, __float2int_rn(v[i].x * inv)));
      int b = max(-127, min(127, __float2int_rn(v[i].y * inv)));
      int c = max(-127, min(127, __float2int_rn(v[i].z * inv)));
      int d = max(-127, min(127, __float2int_rn(v[i].w * inv)));
      drow[lane + 64 * i] = (uint32_t)(a & 255) | ((uint32_t)(b & 255) << 8) |
                            ((uint32_t)(c & 255) << 16) | ((uint32_t)(d & 255) << 24);
    }
    if (lane == 0) { norms[row] = ns; scales[row] = mx * (1.0f / 127.0f); }
  } else {
#pragma unroll
    for (int i = 0; i < 6; ++i) drow[lane + 64 * i] = 0u;
    if (lane == 0) { norms[row] = 1e30f; scales[row] = 0.f; }   // pad never wins
  }
}

// ---- fused 128x256 int8 GEMM + column-min, 2 blocks/CU ----------------
// BM=128, BN=256, 512 thr = 8 waves (2M x 4N), per-wave 64x64 out.
// R20 base, with A FRAGMENTS LOADED GLOBAL->REG (no A in LDS): R20's
// pipes ran serialized (MFMA 44% + LDS 52% = 97% of wall); A was half the
// LDS bytes and its 4x wave-duplication is L1-resident from global. A
// loads (global_load_dwordx4 saddr-form, per-lane const voffset) are
// double-banked aE/aO, issued 1 tile ahead, gated by counted VM --
// per-wave registers need no cross-wave publish. B keeps the 3-buffer
// chunk-XOR LDS path (0 conflicts). LDS traffic halves; A stage gone.
// Gates: steady VM(6) retires a(u)+stageB(u+1), keeps a(u+1)+stageB(u+2)
// (VMEM issue order per phase: 4 a-loads then 2 B-stage gll16).
#define BAR   do { asm volatile("s_barrier" ::: "memory"); \
                   __builtin_amdgcn_sched_barrier(0); } while(0)
#define LGKM0 do { asm volatile("s_waitcnt lgkmcnt(0)" ::: "memory"); \
                   __builtin_amdgcn_sched_barrier(0); } while(0)
#define VM0   asm volatile("s_waitcnt vmcnt(0)" ::: "memory")
#define VM4   asm volatile("s_waitcnt vmcnt(4)" ::: "memory")
#define VM6   asm volatile("s_waitcnt vmcnt(6)" ::: "memory")
#define NOGATE
#define PHI   __builtin_amdgcn_s_setprio(1)
#define PLO   __builtin_amdgcn_s_setprio(0)

#define DSR(dst, base, imm) \
  asm volatile("ds_read_b128 %0, %1 offset:%2" : "=v"(dst) : "v"(base), "i"(imm))

// A fragment loads: bank[m] <- global A row (wm*64+m*16+lr), 16B chunk k16,
// tile column u1*64. voffset per-lane constant; saddr = uniform tile base.
#define GLDA(bank, u1) do { \
  const signed char* _gp = gA + (u1) * 64; \
  asm volatile("global_load_dwordx4 %0, %1, %2" : "=v"(bank[0]) : "v"(vofA[0]), "s"(_gp)); \
  asm volatile("global_load_dwordx4 %0, %1, %2" : "=v"(bank[1]) : "v"(vofA[1]), "s"(_gp)); \
  asm volatile("global_load_dwordx4 %0, %1, %2" : "=v"(bank[2]) : "v"(vofA[2]), "s"(_gp)); \
  asm volatile("global_load_dwordx4 %0, %1, %2" : "=v"(bank[3]) : "v"(vofA[3]), "s"(_gp)); \
} while(0)

// 16 MFMA: 4 m-frags (bank av) x 4 n-frags, K=64
#define MFMA16(av) do { \
  _Pragma("unroll") for (int m_ = 0; m_ < 4; ++m_) \
  _Pragma("unroll") for (int n_ = 0; n_ < 4; ++n_) \
    acc[m_][n_] = __builtin_amdgcn_mfma_i32_16x16x64_i8( \
      __builtin_bit_cast(i32x4, av[m_]), __builtin_bit_cast(i32x4, b[n_]), \
      acc[m_][n_], 0, 0, 0); \
} while(0)

// stage B 256x64 tile -> buf (2 gll16); dest linear, source row tid>>2
// (coalesced 64B segs), chunk permuted (tid&3)^((tid>>3)&3).
#define STAGE_B(sb, ktc) do { \
  const signed char* _g = gB + gOffB + (ktc); \
  gll16(_g,                      &sB[sb][sdst]); \
  gll16(_g + (size_t)128 * DIM,  &sB[sb][8192 + sdst]); \
} while(0)

// one tile phase u: a-loads(u+1) -> other bank; b reads (LDS, buf u%3);
// optional stage B(u+2); LGKM drain (publish invariant); counted gate;
// BAR; 16 MFMA on bank(u&1).
#define PH(buf, AC, AN, u1, SN, SB, KT, GATE) do { \
  GLDA(AN, u1); \
  DSR(b[0], bOff, (buf) * 16384 + 0);    DSR(b[1], bOff, (buf) * 16384 + 1024); \
  DSR(b[2], bOff, (buf) * 16384 + 2048); DSR(b[3], bOff, (buf) * 16384 + 3072); \
  if (SN) STAGE_B(SB, KT); \
  LGKM0; GATE; BAR; PHI; MFMA16(AC); PLO; \
} while(0)

__global__ __launch_bounds__(512, 4)
void gemm_min8(const signed char* __restrict__ fA, const signed char* __restrict__ bB,
               const float* __restrict__ bn, const float* __restrict__ bscale,
               const float* __restrict__ qscale, uint32_t* __restrict__ minbits) {
  __shared__ __align__(16) signed char sB[3][16384];   // 48 KiB (B only)

  const int nwg = GRID3;
  int bid = blockIdx.x;
  const int qch = nwg >> 3, rch = nwg & 7;
  int xcd = bid & 7, loc = bid >> 3;
  int swz = (xcd < rch ? xcd * (qch + 1) : rch * (qch + 1) + (xcd - rch) * qch) + loc;
  int mt = swz % MT3;            // M-fast: consecutive blocks share the B (bank) panel
  int nt = swz / MT3;

  int tid = threadIdx.x;
  int lane = tid & 63, wave = tid >> 6;
  int wm = wave >> 2, wn = wave & 3;
  int lr = lane & 15, k16 = lane >> 4;

  const signed char* gA = fA + (size_t)(mt * 128) * DIM;
  const signed char* gB = bB + (size_t)(nt * 256) * DIM;

  // B staging: row = tid>>2 (coalesced), chunk xor-permuted within 64B
  size_t gOffB = (size_t)(tid >> 2) * DIM + ((tid & 3) ^ ((tid >> 3) & 3)) * 16;
  int sdst = tid * 16;

  // B read base: data (row, k16) at row*64 + (k16 ^ ((row>>1)&3))*16
  int cxB = (k16 ^ ((lr >> 1) & 3)) * 16;
  uint32_t bOff = (uint32_t)(uintptr_t)(lds_i8*)&sB[0][(wn * 64 + lr) * 64 + cxB];

  // A global voffsets (per-lane constants): row (wm*64 + m*16 + lr), chunk k16
  uint32_t vofA[4];
#pragma unroll
  for (int m_ = 0; m_ < 4; ++m_)
    vofA[m_] = (uint32_t)((wm * 64 + m_ * 16 + lr) * DIM + k16 * 16);

  i32x4 acc[4][4] = {};
  f32x4 aE[4], aO[4], b[4];

  // prologue: stage B tiles 0 (buf0) + 1 (buf1); load a(0) -> aE.
  // VM6 retires stB(0) (oldest 2), keeps stB(1)+a(0)=6 (steady invariant);
  // BAR publishes buf0.
  STAGE_B(0, 0);
  STAGE_B(1, 64);
  GLDA(aE, 0);
  VM6; BAR;

  // 3 macro-iters x 6 tiles (tiles 6j..6j+5): buf = u%3, A bank = u&1.
#pragma unroll 1
  for (int j = 0; j < 3; ++j) {
    int u = j * 6, kb = j * 384;
    PH(0, aE, aO, u + 1, 1, 2, kb + 128, VM6);   // tile u
    PH(1, aO, aE, u + 2, 1, 0, kb + 192, VM6);   // u+1
    PH(2, aE, aO, u + 3, 1, 1, kb + 256, VM6);   // u+2
    PH(0, aO, aE, u + 4, 1, 2, kb + 320, VM6);   // u+3
    PH(1, aE, aO, u + 5, 1, 0, kb + 384, VM6);   // u+4
    PH(2, aO, aE, u + 6, 1, 1, kb + 448, VM6);   // u+5
  }
  // tail: tiles 18..23
  PH(0, aE, aO, 19, 1, 2, 1280, VM6);   // 18: stage t20 -> buf2
  PH(1, aO, aE, 20, 1, 0, 1344, VM6);   // 19: stage t21 -> buf0
  PH(2, aE, aO, 21, 1, 1, 1408, VM6);   // 20: stage t22 -> buf1
  PH(0, aO, aE, 22, 1, 2, 1472, VM6);   // 21: stage t23 -> buf2
  PH(1, aE, aO, 23, 0, 0, 0,    VM4);   // 22: load a(23), no stage; VM4
  {  // tile 23: no loads, no stage; VM0 gates a(23)
    DSR(b[0], bOff, 2 * 16384 + 0);    DSR(b[1], bOff, 2 * 16384 + 1024);
    DSR(b[2], bOff, 2 * 16384 + 2048); DSR(b[3], bOff, 2 * 16384 + 3072);
    LGKM0; VM0; BAR; PHI; MFMA16(aO); PLO;
  }

  // epilogue: per-row min over this tile's 256 cols of (bn - 2*sq*sb*idot)
  float bnv[4], bsv[4];
#pragma unroll
  for (int n_ = 0; n_ < 4; ++n_) {
    int col = nt * 256 + wn * 64 + n_ * 16 + lr;
    bnv[n_] = bn[col];
    bsv[n_] = 2.0f * bscale[col];
  }
  int qbase = mt * 128 + wm * 64;
#pragma unroll
  for (int m_ = 0; m_ < 4; ++m_) {
    f32x4 sq = *(const f32x4*)&qscale[qbase + m_ * 16 + (lane >> 4) * 4];
#pragma unroll
    for (int r = 0; r < 4; ++r) {
      float sqr = sq[r];
      float v =          bnv[0] - bsv[0] * sqr * (float)acc[m_][0][r];
      v = fminf(v, bnv[1] - bsv[1] * sqr * (float)acc[m_][1][r]);
      v = fminf(v, bnv[2] - bsv[2] * sqr * (float)acc[m_][2][r]);
      v = fminf(v, bnv[3] - bsv[3] * sqr * (float)acc[m_][3][r]);
      // C/D layout (shape-determined): col = lane&15, row = (lane>>4)*4+r
      v = fminf(v, __shfl_xor(v, 1));
      v = fminf(v, __shfl_xor(v, 2));
      v = fminf(v, __shfl_xor(v, 4));
      v = fminf(v, __shfl_xor(v, 8));
      if (lr == 0) {
        int q = qbase + m_ * 16 + (lane >> 4) * 4 + r;
        atomicMin(&minbits[q], __float_as_uint(v));  // positive floats: uint order == float order
      }
    }
  }
}

// ---- patch scores + per-image max -------------------------------------
__global__ void scores_kernel(const uint32_t* __restrict__ minbits, const float* __restrict__ qn,
                              float* __restrict__ ps, float* __restrict__ img) {
  int q = blockIdx.x * 256 + threadIdx.x;
  if (q >= NQ) return;
  float s = __uint_as_float(minbits[q]) + qn[q];
  ps[q] = s;
  atomicMax((uint32_t*)&img[q / 784], __float_as_uint(s));  // scores > 0
}

// ---- bilinear 28x28 -> 224x224 (half-pixel centers, edge clamp) -------
__global__ void resize_kernel(const float* __restrict__ ps, float* __restrict__ masks) {
  int idx = blockIdx.x * 256 + threadIdx.x;
  if (idx >= NPIX) return;
  int b   = idx / (224 * 224);
  int rem = idx - b * (224 * 224);
  int oy  = rem / 224;
  int ox  = rem - oy * 224;
  float sy = (oy + 0.5f) * 0.125f - 0.5f;
  float sx = (ox + 0.5f) * 0.125f - 0.5f;
  float fy0 = floorf(sy), fx0 = floorf(sx);
  int y0 = (int)fy0, x0 = (int)fx0;
  float fy = sy - fy0, fx = sx - fx0;
  int y0c = min(max(y0, 0), 27),     y1c = min(max(y0 + 1, 0), 27);
  int x0c = min(max(x0, 0), 27),     x1c = min(max(x0 + 1, 0), 27);
  const float* p = ps + b * 784;
  float top = p[y0c * 28 + x0c] * (1.f - fx) + p[y0c * 28 + x1c] * fx;
  float bot = p[y1c * 28 + x0c] * (1.f - fx) + p[y1c * 28 + x1c] * fx;
  masks[idx] = top * (1.f - fy) + bot * fy;
}

// ---- host launch -------------------------------------------------------
extern "C" void kernel_launch(void* const* d_in, const int* in_sizes, int n_in,
                              void* d_out, int out_size, void* d_ws, size_t ws_size,
                              hipStream_t stream) {
  const float* features = (const float*)d_in[0];   // [6272, 1536]
  const float* bank     = (const float*)d_in[1];   // [50000, 1536]

  char* ws = (char*)d_ws;
  size_t off = 0;
  signed char* bankQ = (signed char*)(ws + off); off += (size_t)NBP2 * DIM;   // 77.1 MB
  signed char* featQ = (signed char*)(ws + off); off += (size_t)NQP * DIM;    //  9.8 MB
  float*    bn      = (float*)(ws + off);    off += (size_t)NBP2 * 4;
  float*    qn      = (float*)(ws + off);    off += (size_t)NQP * 4;
  float*    bscale  = (float*)(ws + off);    off += (size_t)NBP2 * 4;
  float*    qscale  = (float*)(ws + off);    off += (size_t)NQP * 4;
  uint32_t* minbits = (uint32_t*)(ws + off); off += (size_t)NQP * 4;
  float*    ps      = (float*)(ws + off);    off += (size_t)NQ * 4;

  float* out_scores = (float*)d_out;       // [8]
  float* masks      = out_scores + 8;      // [8,224,224]

  hipLaunchKernelGGL(init_kernel, dim3(25), dim3(256), 0, stream, minbits, out_scores);
  hipLaunchKernelGGL(quant_rows, dim3(NBP2 / 4), dim3(256), 0, stream, bank, bankQ, bn, bscale, NB, NBP2);
  hipLaunchKernelGGL(quant_rows, dim3(NQP / 4), dim3(256), 0, stream, features, featQ, qn, qscale, NQ, NQP);
  hipLaunchKernelGGL(gemm_min8, dim3(GRID3), dim3(512), 0, stream, featQ, bankQ, bn, bscale, qscale, minbits);
  hipLaunchKernelGGL(scores_kernel, dim3(25), dim3(256), 0, stream, minbits, qn, ps, out_scores);
  hipLaunchKernelGGL(resize_kernel, dim3((NPIX + 255) / 256), dim3(256), 0, stream, ps, masks);
}

// Round 22
// 660.789 us; speedup vs baseline: 1.8772x; 1.8772x over previous
//
#include <hip/hip_runtime.h>
#include <stdint.h>

// ---- Problem constants -------------------------------------------------
#define DIM   1536
#define NQ    6272      // 8 * 28 * 28 queries
#define NQP   6400      // padded to 50 * 128
#define NB    50000     // bank rows
#define NBP2  50176     // padded to 196 * 256
#define MT3   50
#define NT3   196
#define GRID3 (MT3 * NT3)   // 9800
#define NPIX  (8 * 224 * 224)

typedef float f32x4 __attribute__((ext_vector_type(4)));
typedef int   i32x4 __attribute__((ext_vector_type(4)));
typedef __attribute__((address_space(3))) signed char lds_i8;

__device__ inline void gll16(const signed char* g, signed char* l) {
  __builtin_amdgcn_global_load_lds(
      (const __attribute__((address_space(1))) uint32_t*)g,
      (__attribute__((address_space(3))) uint32_t*)l, 16, 0, 0);
}

// ---- init: minbits = +inf, image scores = 0 ---------------------------
__global__ void init_kernel(uint32_t* __restrict__ minbits, float* __restrict__ out_scores) {
  int i = blockIdx.x * 256 + threadIdx.x;
  if (i < NQP) minbits[i] = 0x7F800000u;   // +inf
  if (i < 8)   out_scores[i] = 0.0f;
}

// ---- fp32 -> int8 row quantization + fp32 row norms + scales ----------
__global__ void quant_rows(const float* __restrict__ src, signed char* __restrict__ dst,
                           float* __restrict__ norms, float* __restrict__ scales,
                           int nsrc, int ndst) {
  int row  = blockIdx.x * 4 + (threadIdx.x >> 6);
  int lane = threadIdx.x & 63;
  if (row >= ndst) return;
  uint32_t* drow = (uint32_t*)(dst + (size_t)row * DIM);
  if (row < nsrc) {
    const float4* s = (const float4*)(src + (size_t)row * DIM);
    float4 v[6]; float ns = 0.f, mx = 0.f;
#pragma unroll
    for (int i = 0; i < 6; ++i) {
      v[i] = s[lane + 64 * i];
      ns += v[i].x * v[i].x + v[i].y * v[i].y + v[i].z * v[i].z + v[i].w * v[i].w;
      mx = fmaxf(mx, fmaxf(fmaxf(fabsf(v[i].x), fabsf(v[i].y)),
                           fmaxf(fabsf(v[i].z), fabsf(v[i].w))));
    }
#pragma unroll
    for (int off = 32; off >= 1; off >>= 1) {
      ns += __shfl_xor(ns, off);
      mx = fmaxf(mx, __shfl_xor(mx, off));
    }
    float inv = (mx > 0.f) ? 127.0f / mx : 0.f;
#pragma unroll
    for (int i = 0; i < 6; ++i) {
      int a = max(-127, min(127, __float2int_rn(v[i].x * inv)));
      int b = max(-127, min(127, __float2int_rn(v[i].y * inv)));
      int c = max(-127, min(127, __float2int_rn(v[i].z * inv)));
      int d = max(-127, min(127, __float2int_rn(v[i].w * inv)));
      drow[lane + 64 * i] = (uint32_t)(a & 255) | ((uint32_t)(b & 255) << 8) |
                            ((uint32_t)(c & 255) << 16) | ((uint32_t)(d & 255) << 24);
    }
    if (lane == 0) { norms[row] = ns; scales[row] = mx * (1.0f / 127.0f); }
  } else {
#pragma unroll
    for (int i = 0; i < 6; ++i) drow[lane + 64 * i] = 0u;
    if (lane == 0) { norms[row] = 1e30f; scales[row] = 0.f; }   // pad never wins
  }
}

// ---- fused 128x256 int8 GEMM + column-min, 2 blocks/CU ----------------
// BM=128, BN=256, 512 thr = 8 waves (2M x 4N), per-wave 64x64 out.
// R19 base (2 blocks/CU, 3-buffer rotation, chunk-XOR swizzle, counted
// VM3 gates) + B23-EARLY: PH_A issues ALL 8 reads (a4+b01+b23), waits
// LGKM(2) (LDS in-order: a+b01 drained, b23 stays in flight across the
// barrier, serviced under MFMA n0-1); PH_B has ZERO pre-barrier reads --
// LGKM(0) drains b23 (issued ~1 phase earlier, near-free).
// WAR safety of the leftover: b23 reads buf u%3; the only stage into
// buf u%3 is at PH_A(u+1), which is after PH_B(u)'s LGKM(0)+BAR that
// drained every wave's leftovers. gll16 counts vmcnt, not lgkm.
#define BAR   do { asm volatile("s_barrier" ::: "memory"); \
                   __builtin_amdgcn_sched_barrier(0); } while(0)
#define LGKM(n) do { asm volatile("s_waitcnt lgkmcnt(" #n ")" ::: "memory"); \
                     __builtin_amdgcn_sched_barrier(0); } while(0)
#define VM0   asm volatile("s_waitcnt vmcnt(0)" ::: "memory")
#define VM3   asm volatile("s_waitcnt vmcnt(3)" ::: "memory")
#define NOGATE
#define PHI   __builtin_amdgcn_s_setprio(1)
#define PLO   __builtin_amdgcn_s_setprio(0)

#define DSR(dst, base, imm) \
  asm volatile("ds_read_b128 %0, %1 offset:%2" : "=v"(dst) : "v"(base), "i"(imm))

// 8 MFMA: 4 m-frags x 2 n-frags (nb, nb+1), K=64
#define MFMA8N(nb, bb) do { \
  _Pragma("unroll") for (int m_ = 0; m_ < 4; ++m_) \
  _Pragma("unroll") for (int n_ = 0; n_ < 2; ++n_) \
    acc[m_][(nb) + n_] = __builtin_amdgcn_mfma_i32_16x16x64_i8( \
      __builtin_bit_cast(i32x4, a[m_]), __builtin_bit_cast(i32x4, bb[n_]), \
      acc[m_][(nb) + n_], 0, 0, 0); \
} while(0)

// stage tile -> buf: A 128x64 (1 gll16), B 256x64 (2 gll16); dest linear,
// source row = tid>>2 (coalesced 64B segs), chunk (tid&3)^((tid>>3)&3).
#define STAGE_AB(sb, ktc) do { \
  gll16(gA + gOffA + (ktc), &sA[sb][sdst]); \
  const signed char* _g = gB + gOffA + (ktc); \
  gll16(_g,                      &sB[sb][sdst]); \
  gll16(_g + (size_t)128 * DIM,  &sB[sb][8192 + sdst]); \
} while(0)

// PH_A: all 8 reads of buf (b23 last); optional stage(u+2); LGKM(2)
// keeps b23 in flight; BAR; MFMA n0-1.
#define PH_A(buf, SN, sb, ktc) do { \
  DSR(a[0], aOff, (buf) * 8192 + 0);    DSR(a[1], aOff, (buf) * 8192 + 1024); \
  DSR(a[2], aOff, (buf) * 8192 + 2048); DSR(a[3], aOff, (buf) * 8192 + 3072); \
  DSR(b01[0], bOff, (buf) * 16384 + 0); DSR(b01[1], bOff, (buf) * 16384 + 1024); \
  DSR(b23[0], bOff, (buf) * 16384 + 2048); DSR(b23[1], bOff, (buf) * 16384 + 3072); \
  if (SN) STAGE_AB(sb, ktc); \
  LGKM(2); BAR; PHI; MFMA8N(0, b01); PLO; \
} while(0)

// PH_B: no reads; LGKM(0) drains b23; counted gate; BAR; MFMA n2-3.
#define PH_B(GATE) do { \
  LGKM(0); GATE; BAR; PHI; MFMA8N(2, b23); PLO; \
} while(0)

__global__ __launch_bounds__(512, 4)
void gemm_min8(const signed char* __restrict__ fA, const signed char* __restrict__ bB,
               const float* __restrict__ bn, const float* __restrict__ bscale,
               const float* __restrict__ qscale, uint32_t* __restrict__ minbits) {
  __shared__ __align__(16) signed char sA[3][8192];    // 24 KiB
  __shared__ __align__(16) signed char sB[3][16384];   // 48 KiB

  const int nwg = GRID3;
  int bid = blockIdx.x;
  const int qch = nwg >> 3, rch = nwg & 7;
  int xcd = bid & 7, loc = bid >> 3;
  int swz = (xcd < rch ? xcd * (qch + 1) : rch * (qch + 1) + (xcd - rch) * qch) + loc;
  int mt = swz % MT3;            // M-fast: consecutive blocks share the B (bank) panel
  int nt = swz / MT3;

  int tid = threadIdx.x;
  int lane = tid & 63, wave = tid >> 6;
  int wm = wave >> 2, wn = wave & 3;
  int lr = lane & 15, k16 = lane >> 4;

  const signed char* gA = fA + (size_t)(mt * 128) * DIM;
  const signed char* gB = bB + (size_t)(nt * 256) * DIM;

  // staging: row = tid>>2 (A rows 0-127; B also +128), chunk xor-permuted
  size_t gOffA = (size_t)(tid >> 2) * DIM + ((tid & 3) ^ ((tid >> 3) & 3)) * 16;
  int sdst = tid * 16;

  // read bases: data (row, k16) at row*64 + (k16 ^ ((row>>1)&3))*16
  int cxA = (k16 ^ ((lr >> 1) & 3)) * 16;
  uint32_t aOff = (uint32_t)(uintptr_t)(lds_i8*)&sA[0][(wm * 64 + lr) * 64 + cxA];
  uint32_t bOff = (uint32_t)(uintptr_t)(lds_i8*)&sB[0][(wn * 64 + lr) * 64 + cxA];

  i32x4 acc[4][4] = {};
  f32x4 a[4], b01[2], b23[2];

  // prologue: stage tiles 0 (buf0) + 1 (buf1); VM3 retires t0's 3 gll16
  // (keeps t1's 3 in flight, retired at tile 0's PH_B gate); publish.
  STAGE_AB(0, 0);
  STAGE_AB(1, 64);
  VM3; BAR;

  // 7 full iterations: tiles 3j, 3j+1, 3j+2 in bufs 0,1,2; each tile u
  // stages tile u+2 at PH_A; VM3 gate at PH_B retires tile u+1's stages.
#pragma unroll 1
  for (int j = 0; j < 7; ++j) {
    int kb = j * 192;
    PH_A(0, 1, 2, kb + 128); PH_B(VM3);   // tile 3j   : stage 3j+2 -> buf2
    PH_A(1, 1, 0, kb + 192); PH_B(VM3);   // tile 3j+1 : stage 3j+3 -> buf0
    PH_A(2, 1, 1, kb + 256); PH_B(VM3);   // tile 3j+2 : stage 3j+4 -> buf1
  }
  // tail: tiles 21 (buf0, stages t23->buf2), 22 (buf1), 23 (buf2)
  PH_A(0, 1, 2, 1472); PH_B(VM3);
  PH_A(1, 0, 0, 0);    PH_B(VM0);
  PH_A(2, 0, 0, 0);    PH_B(NOGATE);

  // epilogue: per-row min over this tile's 256 cols of (bn - 2*sq*sb*idot)
  float bnv[4], bsv[4];
#pragma unroll
  for (int n_ = 0; n_ < 4; ++n_) {
    int col = nt * 256 + wn * 64 + n_ * 16 + lr;
    bnv[n_] = bn[col];
    bsv[n_] = 2.0f * bscale[col];
  }
  int qbase = mt * 128 + wm * 64;
#pragma unroll
  for (int m_ = 0; m_ < 4; ++m_) {
    f32x4 sq = *(const f32x4*)&qscale[qbase + m_ * 16 + (lane >> 4) * 4];
#pragma unroll
    for (int r = 0; r < 4; ++r) {
      float sqr = sq[r];
      float v =          bnv[0] - bsv[0] * sqr * (float)acc[m_][0][r];
      v = fminf(v, bnv[1] - bsv[1] * sqr * (float)acc[m_][1][r]);
      v = fminf(v, bnv[2] - bsv[2] * sqr * (float)acc[m_][2][r]);
      v = fminf(v, bnv[3] - bsv[3] * sqr * (float)acc[m_][3][r]);
      // C/D layout (shape-determined): col = lane&15, row = (lane>>4)*4+r
      v = fminf(v, __shfl_xor(v, 1));
      v = fminf(v, __shfl_xor(v, 2));
      v = fminf(v, __shfl_xor(v, 4));
      v = fminf(v, __shfl_xor(v, 8));
      if (lr == 0) {
        int q = qbase + m_ * 16 + (lane >> 4) * 4 + r;
        atomicMin(&minbits[q], __float_as_uint(v));  // positive floats: uint order == float order
      }
    }
  }
}

// ---- patch scores + per-image max -------------------------------------
__global__ void scores_kernel(const uint32_t* __restrict__ minbits, const float* __restrict__ qn,
                              float* __restrict__ ps, float* __restrict__ img) {
  int q = blockIdx.x * 256 + threadIdx.x;
  if (q >= NQ) return;
  float s = __uint_as_float(minbits[q]) + qn[q];
  ps[q] = s;
  atomicMax((uint32_t*)&img[q / 784], __float_as_uint(s));  // scores > 0
}

// ---- bilinear 28x28 -> 224x224 (half-pixel centers, edge clamp) -------
__global__ void resize_kernel(const float* __restrict__ ps, float* __restrict__ masks) {
  int idx = blockIdx.x * 256 + threadIdx.x;
  if (idx >= NPIX) return;
  int b   = idx / (224 * 224);
  int rem = idx - b * (224 * 224);
  int oy  = rem / 224;
  int ox  = rem - oy * 224;
  float sy = (oy + 0.5f) * 0.125f - 0.5f;
  float sx = (ox + 0.5f) * 0.125f - 0.5f;
  float fy0 = floorf(sy), fx0 = floorf(sx);
  int y0 = (int)fy0, x0 = (int)fx0;
  float fy = sy - fy0, fx = sx - fx0;
  int y0c = min(max(y0, 0), 27),     y1c = min(max(y0 + 1, 0), 27);
  int x0c = min(max(x0, 0), 27),     x1c = min(max(x0 + 1, 0), 27);
  const float* p = ps + b * 784;
  float top = p[y0c * 28 + x0c] * (1.f - fx) + p[y0c * 28 + x1c] * fx;
  float bot = p[y1c * 28 + x0c] * (1.f - fx) + p[y1c * 28 + x1c] * fx;
  masks[idx] = top * (1.f - fy) + bot * fy;
}

// ---- host launch -------------------------------------------------------
extern "C" void kernel_launch(void* const* d_in, const int* in_sizes, int n_in,
                              void* d_out, int out_size, void* d_ws, size_t ws_size,
                              hipStream_t stream) {
  const float* features = (const float*)d_in[0];   // [6272, 1536]
  const float* bank     = (const float*)d_in[1];   // [50000, 1536]

  char* ws = (char*)d_ws;
  size_t off = 0;
  signed char* bankQ = (signed char*)(ws + off); off += (size_t)NBP2 * DIM;   // 77.1 MB
  signed char* featQ = (signed char*)(ws + off); off += (size_t)NQP * DIM;    //  9.8 MB
  float*    bn      = (float*)(ws + off);    off += (size_t)NBP2 * 4;
  float*    qn      = (float*)(ws + off);    off += (size_t)NQP * 4;
  float*    bscale  = (float*)(ws + off);    off += (size_t)NBP2 * 4;
  float*    qscale  = (float*)(ws + off);    off += (size_t)NQP * 4;
  uint32_t* minbits = (uint32_t*)(ws + off); off += (size_t)NQP * 4;
  float*    ps      = (float*)(ws + off);    off += (size_t)NQ * 4;

  float* out_scores = (float*)d_out;       // [8]
  float* masks      = out_scores + 8;      // [8,224,224]

  hipLaunchKernelGGL(init_kernel, dim3(25), dim3(256), 0, stream, minbits, out_scores);
  hipLaunchKernelGGL(quant_rows, dim3(NBP2 / 4), dim3(256), 0, stream, bank, bankQ, bn, bscale, NB, NBP2);
  hipLaunchKernelGGL(quant_rows, dim3(NQP / 4), dim3(256), 0, stream, features, featQ, qn, qscale, NQ, NQP);
  hipLaunchKernelGGL(gemm_min8, dim3(GRID3), dim3(512), 0, stream, featQ, bankQ, bn, bscale, qscale, minbits);
  hipLaunchKernelGGL(scores_kernel, dim3(25), dim3(256), 0, stream, minbits, qn, ps, out_scores);
  hipLaunchKernelGGL(resize_kernel, dim3((NPIX + 255) / 256), dim3(256), 0, stream, ps, masks);
}